// Round 5
// baseline (607.419 us; speedup 1.0000x reference)
//
#include <hip/hip_runtime.h>

// MaskedBatchNorm2d: B=16, C=64, W=256, H=256, fp32.
// Identity: masked-out locations are exactly 0 in all channels, so masked
// per-channel sums == full sums and out = x*inv[c] everywhere; exact-
// cancellation "dirty" locations (~never) corrected in finalize + fixup.
//
// R1: global atomic storm (823us). R2: barrier convoys, 2 syncs per 256-loc
// tile -> 50% memory duty cycle (172us pass1). R3: cooperative launch
// silently failed — abandoned. R4: nontemporal builtin needs native vector
// type (HIP float4 is a class) — fixed with ext_vector_type alias.
// This round: pass1 with ONE barrier pair total — each wave accumulates its
// 16-channel registers AND writes per-location partials to its OWN LDS
// region (no cross-wave hazard); combine once at the end.

#define NB 16
#define DIRTY_CAP 512
#define EPS 0.001f
#define GRID1 1024            // pass1 blocks: 1024 locations each

typedef float vfloat4 __attribute__((ext_vector_type(4)));  // native vec for nontemporal

// ws layout (float units):
//  sqPart   [0 .. 131071]      1024 rows x 128 (S cols 0..63 | Q cols 64..127)
//  nPart    [131072 .. 132095] 1024 uints
//  dirtyCnt [132160]           uint (zeroed by memset)
//  inv      [132224 .. 132287] 64 floats
//  padArr   [132288 .. 132303] 16 ints
//  dirtyLoc [132352 .. 132863] DIRTY_CAP ints

__global__ __launch_bounds__(256, 4)
void mbn_pass1(const float* __restrict__ x, float* __restrict__ sqPart,
               unsigned* __restrict__ nPart, unsigned* __restrict__ dirtyCnt,
               int* __restrict__ dirtyLoc) {
    __shared__ float lds_s[4][1024];     // per-wave per-location partial sums
    __shared__ float lds_a[4][1024];     // per-wave per-location partial |x| sums
    __shared__ unsigned cntw[4];

    const int tid  = threadIdx.x;
    const int wave = tid >> 6;
    const int lane = tid & 63;
    const int blk  = blockIdx.x;
    const int b    = blk >> 6;            // 64 blocks per batch
    const int whb0 = (blk & 63) << 10;    // 1024 locations per block

    float sAcc[16], qAcc[16];
#pragma unroll
    for (int j = 0; j < 16; ++j) { sAcc[j] = 0.f; qAcc[j] = 0.f; }

    const float* wbase = x + (((size_t)(b * 64 + wave * 16)) << 16) + whb0 + lane * 4;

    // ---- hot loop: NO barriers. 4 chunks x 16 channels, 1 KB per load ----
#pragma unroll
    for (int j = 0; j < 4; ++j) {                  // chunk of 256 locations
        const float* cb = wbase + j * 256;
        float4 sp = make_float4(0.f, 0.f, 0.f, 0.f);
        float4 aa = make_float4(0.f, 0.f, 0.f, 0.f);
#pragma unroll
        for (int c = 0; c < 16; ++c) {             // this wave's 16 channels
            float4 v = *(const float4*)(cb + ((size_t)c << 16));
            sp.x += v.x; sp.y += v.y; sp.z += v.z; sp.w += v.w;
            aa.x += fabsf(v.x); aa.y += fabsf(v.y); aa.z += fabsf(v.z); aa.w += fabsf(v.w);
            sAcc[c] += (v.x + v.y) + (v.z + v.w);
            qAcc[c] = fmaf(v.x, v.x, qAcc[c]);
            qAcc[c] = fmaf(v.y, v.y, qAcc[c]);
            qAcc[c] = fmaf(v.z, v.z, qAcc[c]);
            qAcc[c] = fmaf(v.w, v.w, qAcc[c]);
        }
        // own region: no cross-wave hazard, no barrier needed
        *(float4*)&lds_s[wave][j * 256 + lane * 4] = sp;
        *(float4*)&lds_a[wave][j * 256 + lane * 4] = aa;
    }
    __syncthreads();                               // barrier #1 (only one!)

    // ---- combine: thread t owns locations 4t..4t+3 ----
    float4 s0 = *(const float4*)&lds_s[0][tid * 4];
    float4 s1 = *(const float4*)&lds_s[1][tid * 4];
    float4 s2 = *(const float4*)&lds_s[2][tid * 4];
    float4 s3 = *(const float4*)&lds_s[3][tid * 4];
    float4 a0 = *(const float4*)&lds_a[0][tid * 4];
    float4 a1 = *(const float4*)&lds_a[1][tid * 4];
    float4 a2 = *(const float4*)&lds_a[2][tid * 4];
    float4 a3 = *(const float4*)&lds_a[3][tid * 4];
    float sx = (s0.x + s1.x) + (s2.x + s3.x);
    float sy = (s0.y + s1.y) + (s2.y + s3.y);
    float sz = (s0.z + s1.z) + (s2.z + s3.z);
    float sw = (s0.w + s1.w) + (s2.w + s3.w);
    float ax = (a0.x + a1.x) + (a2.x + a3.x);
    float ay = (a0.y + a1.y) + (a2.y + a3.y);
    float az = (a0.z + a1.z) + (a2.z + a3.z);
    float aw = (a0.w + a1.w) + (a2.w + a3.w);
    bool m0 = (sx != 0.f), m1 = (sy != 0.f), m2 = (sz != 0.f), m3 = (sw != 0.f);
    unsigned cnt = (m0 ? 1u : 0u) + (m1 ? 1u : 0u) + (m2 ? 1u : 0u) + (m3 ? 1u : 0u);
    // exact-cancellation dirty path: ~never taken
    if ((!m0 && ax != 0.f) | (!m1 && ay != 0.f) | (!m2 && az != 0.f) | (!m3 && aw != 0.f)) {
        bool d[4] = { !m0 && ax != 0.f, !m1 && ay != 0.f, !m2 && az != 0.f, !m3 && aw != 0.f };
        for (int k = 0; k < 4; ++k) if (d[k]) {
            unsigned id = atomicAdd(dirtyCnt, 1u);
            if (id < DIRTY_CAP) dirtyLoc[id] = (b << 16) | (whb0 + tid * 4 + k);
        }
    }
#pragma unroll
    for (int off = 32; off; off >>= 1) cnt += __shfl_xor(cnt, off);
    if (lane == 0) cntw[wave] = cnt;

    // ---- per-channel wave-reduce; plain stores (no global atomics) ----
#pragma unroll
    for (int j = 0; j < 16; ++j) {
        float sv = sAcc[j], qv = qAcc[j];
#pragma unroll
        for (int off = 32; off; off >>= 1) {
            sv += __shfl_xor(sv, off);
            qv += __shfl_xor(qv, off);
        }
        if (lane == 0) {
            sqPart[blk * 128 + wave * 16 + j]      = sv;
            sqPart[blk * 128 + 64 + wave * 16 + j] = qv;
        }
    }
    __syncthreads();                               // barrier #2
    if (tid == 0) nPart[blk] = cntw[0] + cntw[1] + cntw[2] + cntw[3];
}

__global__ __launch_bounds__(1024)
void mbn_finalize(const float* __restrict__ x, const float* __restrict__ sqPart,
                  const unsigned* __restrict__ nPart,
                  const unsigned* __restrict__ dirtyCnt, const int* __restrict__ dirtyLoc,
                  float* __restrict__ inv, int* __restrict__ padOut) {
    __shared__ float red[1024];
    __shared__ float sq[128];
    __shared__ unsigned ntot[16];
    const int t = threadIdx.x;              // 1024 threads
    const int col = t & 127, grp = t >> 7;  // 8 row-groups of 128 rows

    float acc = 0.f;
    const float* p = sqPart + (size_t)grp * 128 * 128 + col;
#pragma unroll 8
    for (int r = 0; r < 128; ++r) acc += p[(size_t)r * 128];
    red[t] = acc;

    if (t < 16) {                           // batch mask totals
        unsigned s = 0;
        const unsigned* np = nPart + t * 64;
#pragma unroll 8
        for (int i = 0; i < 64; ++i) s += np[i];
        ntot[t] = s;
    }
    __syncthreads();
    if (t < 128) {
        float v = 0.f;
#pragma unroll
        for (int g = 0; g < 8; ++g) v += red[g * 128 + t];
        sq[t] = v;
    }
    __syncthreads();

    if (t < 64) {
        const int c = t;
        unsigned nmax = 0;
#pragma unroll
        for (int b = 0; b < NB; ++b) { unsigned nb = ntot[b]; nmax = nb > nmax ? nb : nmax; }
        const float total = (float)(16u * nmax);   // B*Nmax, exact in fp32

        float s = sq[c], q = sq[64 + c];
        unsigned cnt = *dirtyCnt; if (cnt > DIRTY_CAP) cnt = DIRTY_CAP;
        for (unsigned i = 0; i < cnt; ++i) {       // ~never runs
            int loc = dirtyLoc[i];
            int b = loc >> 16, wh = loc & 65535;
            float v = x[(((size_t)(b * 64 + c)) << 16) + wh];
            s -= v; q -= v * v;
        }
        float p1 = 0.f, p2 = 0.f;
#pragma unroll
        for (int b = 0; b < NB; ++b) {
            float padf = (float)(nmax - ntot[b]);
            float v00  = x[((size_t)(b * 64 + c)) << 16];
            p1 = fmaf(padf, v00, p1);
            p2 = fmaf(padf, v00 * v00, p2);
            if (c == 0) padOut[b] = (int)(nmax - ntot[b]);
        }
        float mean = (s + p1) / total;
        float var  = (q + p2) / total - mean * mean;   // algebraic identity w/ ref
        inv[c] = 1.0f / sqrtf(var + EPS);
    }
}

__global__ __launch_bounds__(256)
void mbn_pass2(const vfloat4* __restrict__ x4, vfloat4* __restrict__ out4,
               const float* __restrict__ inv) {
    // 4096 blocks: each scales one contiguous quarter-plane (4096 float4)
    const int blk = blockIdx.x;
    const float sc = inv[(blk >> 2) & 63];            // 4 blocks per (b,c) plane
    const size_t base = ((size_t)blk << 12) + threadIdx.x;
#pragma unroll
    for (int k = 0; k < 16; ++k) {
        size_t i = base + (size_t)k * 256;
        vfloat4 v = x4[i];
        v *= sc;
        __builtin_nontemporal_store(v, &out4[i]);     // out is never re-read
    }
}

__global__ void mbn_fixup(const float* __restrict__ x, float* __restrict__ out,
                          const unsigned* __restrict__ dirtyCnt, const int* __restrict__ dirtyLoc,
                          const int* __restrict__ padArr) {
    const int c = threadIdx.x;  // 64
    unsigned cnt = *dirtyCnt; if (cnt > DIRTY_CAP) cnt = DIRTY_CAP;
    for (unsigned i = 0; i < cnt; ++i) {
        int loc = dirtyLoc[i];
        int b = loc >> 16, wh = loc & 65535;
        if (wh == 0 && padArr[b] > 0) continue;   // (0,0) override wins: keep x00*inv
        size_t idx = (((size_t)(b * 64 + c)) << 16) + wh;
        out[idx] = x[idx];                        // m=0 location w/ nonzero x: out = x
    }
}

extern "C" void kernel_launch(void* const* d_in, const int* in_sizes, int n_in,
                              void* d_out, int out_size, void* d_ws, size_t ws_size,
                              hipStream_t stream) {
    const float* x = (const float*)d_in[0];
    float* out = (float*)d_out;
    float* wsf = (float*)d_ws;

    float*    sqPart   = wsf;
    unsigned* nPart    = (unsigned*)(wsf + 131072);
    unsigned* dirtyCnt = (unsigned*)(wsf + 132160);
    float*    inv      = wsf + 132224;
    int*      padArr   = (int*)(wsf + 132288);
    int*      dirtyLoc = (int*)(wsf + 132352);

    (void)hipMemsetAsync((char*)d_ws + 132160 * 4, 0, 64, stream);  // dirtyCnt only

    mbn_pass1<<<GRID1, 256, 0, stream>>>(x, sqPart, nPart, dirtyCnt, dirtyLoc);
    mbn_finalize<<<1, 1024, 0, stream>>>(x, sqPart, nPart, dirtyCnt, dirtyLoc, inv, padArr);
    mbn_pass2<<<4096, 256, 0, stream>>>((const vfloat4*)x, (vfloat4*)out, inv);
    mbn_fixup<<<1, 64, 0, stream>>>(x, out, dirtyCnt, dirtyLoc, padArr);
}